// Round 16
// baseline (97.454 us; speedup 1.0000x reference)
//
#include <hip/hip_runtime.h>

// Inverse DTCWT (biort legall) — round-15 superstage kernel (NT stores,
// cached reads) with TH=256: one plane per block (256 blocks, 1/CU),
// halo overhead 1.6% (130 stages per 128 owned pairs), one pipeline
// warm-up per block. Ring-2 32KB supers, counted WAIT(16).

#define Hh 256
#define Ww 256
#define W2 128
#define SBsz (128 * 128)
#define TH 256
#define NST 130     // consumed row-pairs t = 0..129 (pairs -1 .. 128, clamped)
#define NSUP 33     // superstages of 4 pairs (last one half-used)
#define YBASE 6144  // Yl region float offset inside a super buffer
#define SUPSZ 8192  // floats per super buffer (32 KB)

typedef float f32x2 __attribute__((ext_vector_type(2)));

__device__ __forceinline__ int reflect_idx(int m, int N) {
    if (m < 0) m = -m - 1;
    if (m >= N) m = 2 * N - 1 - m;
    return m;
}

#define WAIT16() asm volatile("s_waitcnt vmcnt(16)" ::: "memory")
#define WAIT0()  asm volatile("s_waitcnt vmcnt(0)" ::: "memory")
#define LGKM0()  asm volatile("s_waitcnt lgkmcnt(0)" ::: "memory")
#define BAR()    __builtin_amdgcn_s_barrier()

__global__ __launch_bounds__(128) void dtcwt_inv(
    const float* __restrict__ Yl,
    const float* __restrict__ Yhr,
    const float* __restrict__ Yhi,
    const float* __restrict__ g0o,
    const float* __restrict__ g1o,
    float* __restrict__ out)
{
    const float SC = 0.70710678118654752440f;  // sqrt(0.5)
    __shared__ float ring[2][SUPSZ];

    const int c = threadIdx.x;        // 0..127: output cols 2c, 2c+1
    const int plane = blockIdx.x;
    const int i0 = 0;
    const int ip0 = 0;

    const float* yl  = Yl  + (size_t)plane * (Hh * Ww);
    const float* phr = Yhr + (size_t)plane * 6 * SBsz;
    const float* phi = Yhi + (size_t)plane * 6 * SBsz;
    float* outp = out + (size_t)plane * (Hh * Ww);

    float g0[3], g1[5];
#pragma unroll
    for (int t = 0; t < 3; ++t) g0[t] = g0o[t];
#pragma unroll
    for (int t = 0; t < 5; ++t) g1[t] = g1o[t];

    // Quad-col tables: qcols 2c-2 .. 2c+3 -> subband col (even slots) + parity.
    int jcs[3], vq[6];
#pragma unroll
    for (int k = 0; k < 6; ++k) {
        int qq = reflect_idx(2 * c - 2 + k, Ww);
        if ((k & 1) == 0) jcs[k >> 1] = qq >> 1;
        vq[k] = qq & 1;
    }
    const int ylc0 = reflect_idx(2 * c - 1, Ww);
    const int ylc3 = reflect_idx(2 * c + 2, Ww);

    // ---- superstage staging ----
    // Super buffer layout (floats): band b (0..5 real, 6..11 imag) rows r=0..3
    // at b*512 + r*128 + col; Yl rows rr=0..7 at YBASE + rr*256 + col.
    // 32 chunks of 1KB: chunks 0..23 = (band b, half h): rows 2h,2h+1;
    // chunks 24..31 = Yl row rr. Wave w issues chunks w*16 .. w*16+15.
    const int wv = c >> 6, lane = c & 63;
    auto issueSuper = [&](int g) {
        float* B = ring[g & 1];
#pragma unroll
        for (int rep = 0; rep < 16; ++rep) {
            const int chunk = wv * 16 + rep;
            const float* src;
            int dstoff;
            if (chunk < 24) {
                const int b = chunk >> 1, h = chunk & 1;
                int t = 4 * g + 2 * h + (lane >> 5);
                int v = ip0 - 1 + t;
                int ip = v < 0 ? 0 : (v > 127 ? 127 : v);
                const float* bq = (b < 6) ? phr + (size_t)b * SBsz
                                          : phi + (size_t)(b - 6) * SBsz;
                src = bq + ip * W2 + ((lane & 31) << 2);
                dstoff = b * 512 + h * 256;
            } else {
                const int rr = chunk - 24;
                int t = 4 * g + (rr >> 1);
                int v = ip0 - 1 + t;
                int ip = v < 0 ? 0 : (v > 127 ? 127 : v);
                src = yl + (size_t)(2 * ip + (rr & 1)) * Ww + (lane << 2);
                dstoff = YBASE + rr * 256;
            }
            __builtin_amdgcn_global_load_lds(
                (const __attribute__((address_space(1))) void*)src,
                (__attribute__((address_space(3))) void*)(B + dstoff),
                16, 0, 0);
        }
    };

    float w1a[4], w1b[4], w2a[4], w2b[4];  // column windows, cols 2c / 2c+1
    const float SCg1[5] = {g1[0]*SC, g1[1]*SC, g1[2]*SC, g1[3]*SC, g1[4]*SC};
    const float SCg0[3] = {g0[0]*SC, g0[1]*SC, g0[2]*SC};

    auto computeStage = [&](int t, int r, const float* B) {
        const int ro = r * 128;
        // Yl row filter, windows cols 2c-1 .. 2c+2 (rows 2r, 2r+1 of super)
        const int ya_o = YBASE + 512 * r, yb_o = ya_o + 256;
        float ya0 = B[ya_o + ylc0],    ya1 = B[ya_o + 2*c];
        float ya2 = B[ya_o + 2*c + 1], ya3 = B[ya_o + ylc3];
        float yb0 = B[yb_o + ylc0],    yb1 = B[yb_o + 2*c];
        float yb2 = B[yb_o + 2*c + 1], yb3 = B[yb_o + ylc3];
        float y1_00 = g0[0]*ya0 + g0[1]*ya1 + g0[2]*ya2;
        float y1_01 = g0[0]*ya1 + g0[1]*ya2 + g0[2]*ya3;
        float y1_10 = g0[0]*yb0 + g0[1]*yb1 + g0[2]*yb2;
        float y1_11 = g0[0]*yb1 + g0[1]*yb2 + g0[2]*yb3;
        float y2_00 = 0.f, y2_01 = 0.f, y2_10 = 0.f, y2_11 = 0.f;
#pragma unroll
        for (int m = 0; m < 3; ++m) {
            const int col = ro + jcs[m];
            float lr1 = B[col],        lr2 = B[2560 + col];   // lh 0,5
            float hr1 = B[1024 + col], hr2 = B[1536 + col];   // hl 2,3
            float er1 = B[512 + col],  er2 = B[2048 + col];   // hh 1,4
            float li1 = B[3072 + col],        li2 = B[3072 + 2560 + col];
            float hi1 = B[3072 + 1024 + col], hi2 = B[3072 + 1536 + col];
            float ei1 = B[3072 + 512 + col],  ei2 = B[3072 + 2048 + col];
            float lSr = lr1 + lr2, lSi = li1 + li2, lDi = li1 - li2, lDr = lr2 - lr1;
            float hSr = hr1 + hr2, hSi = hi1 + hi2, hDi = hi1 - hi2, hDr = hr2 - hr1;
            float eSr = er1 + er2, eSi = ei1 + ei2, eDi = ei1 - ei2, eDr = er2 - er1;
#pragma unroll
            for (int kk = 0; kk < 2; ++kk) {
                const int k = 2 * m + kk;
                const int vv = vq[k];
                float qh0 = vv ? hSi : hSr, qh1 = vv ? hDr : hDi;
                float qe0 = vv ? eSi : eSr, qe1 = vv ? eDr : eDi;
                float ql0 = vv ? lSi : lSr, ql1 = vv ? lDr : lDi;
                if (k <= 4) {
                    y1_00 += SCg1[k] * qh0; y1_10 += SCg1[k] * qh1;
                    y2_00 += SCg1[k] * qe0; y2_10 += SCg1[k] * qe1;
                }
                if (k >= 1) {
                    y1_01 += SCg1[k - 1] * qh0; y1_11 += SCg1[k - 1] * qh1;
                    y2_01 += SCg1[k - 1] * qe0; y2_11 += SCg1[k - 1] * qe1;
                }
                if (k >= 1 && k <= 3) {
                    y2_00 += SCg0[k - 1] * ql0; y2_10 += SCg0[k - 1] * ql1;
                }
                if (k >= 2 && k <= 4) {
                    y2_01 += SCg0[k - 2] * ql0; y2_11 += SCg0[k - 2] * ql1;
                }
            }
        }
        // vertical reflection order + column-filter sliding window
        int v = ip0 - 1 + t;
        bool rev = (v < 0) || (v > 127);
        float a1A = rev ? y1_10 : y1_00, a2A = rev ? y2_10 : y2_00;
        float b1A = rev ? y1_00 : y1_10, b2A = rev ? y2_00 : y2_10;
        float a1B = rev ? y1_11 : y1_01, a2B = rev ? y2_11 : y2_01;
        float b1B = rev ? y1_01 : y1_11, b2B = rev ? y2_01 : y2_11;
        if (t == 0) {
            w1a[0]=a1A; w1a[1]=b1A; w2a[0]=a2A; w2a[1]=b2A;
            w1b[0]=a1B; w1b[1]=b1B; w2b[0]=a2B; w2b[1]=b2B;
        } else if (t == 1) {
            w1a[2]=a1A; w1a[3]=b1A; w2a[2]=a2A; w2a[3]=b2A;
            w1b[2]=a1B; w1b[3]=b1B; w2b[2]=a2B; w2b[3]=b2B;
        } else {
            const int r0 = i0 + 2 * (t - 2);
            float o0A = g0[0]*w1a[1] + g0[1]*w1a[2] + g0[2]*w1a[3]
                      + g1[0]*w2a[0] + g1[1]*w2a[1] + g1[2]*w2a[2]
                      + g1[3]*w2a[3] + g1[4]*a2A;
            float o1A = g0[0]*w1a[2] + g0[1]*w1a[3] + g0[2]*a1A
                      + g1[0]*w2a[1] + g1[1]*w2a[2] + g1[2]*w2a[3]
                      + g1[3]*a2A + g1[4]*b2A;
            float o0B = g0[0]*w1b[1] + g0[1]*w1b[2] + g0[2]*w1b[3]
                      + g1[0]*w2b[0] + g1[1]*w2b[1] + g1[2]*w2b[2]
                      + g1[3]*w2b[3] + g1[4]*a2B;
            float o1B = g0[0]*w1b[2] + g0[1]*w1b[3] + g0[2]*a1B
                      + g1[0]*w2b[1] + g1[1]*w2b[2] + g1[2]*w2b[3]
                      + g1[3]*a2B + g1[4]*b2B;
            f32x2 v0; v0.x = o0A; v0.y = o0B;
            f32x2 v1; v1.x = o1A; v1.y = o1B;
            __builtin_nontemporal_store(v0, (f32x2*)(outp + (size_t)r0 * Ww + 2 * c));
            __builtin_nontemporal_store(v1, (f32x2*)(outp + (size_t)(r0 + 1) * Ww + 2 * c));
            w1a[0]=w1a[2]; w1a[1]=w1a[3]; w1a[2]=a1A; w1a[3]=b1A;
            w2a[0]=w2a[2]; w2a[1]=w2a[3]; w2a[2]=a2A; w2a[3]=b2A;
            w1b[0]=w1b[2]; w1b[1]=w1b[3]; w1b[2]=a1B; w1b[3]=b1B;
            w2b[0]=w2b[2]; w2b[1]=w2b[3]; w2b[2]=a2B; w2b[3]=b2B;
        }
    };

    // ---- pipeline over superstages: counted WAIT(16), never 0 mid-loop ----
    issueSuper(0); issueSuper(1);
    for (int g = 0; g < NSUP; ++g) {
        if (g + 1 < NSUP) { WAIT16(); } else { WAIT0(); }
        LGKM0(); BAR();                 // super g fully landed (both waves)
        const float* B = ring[g & 1];
#pragma unroll
        for (int r = 0; r < 4; ++r) {
            const int t = 4 * g + r;
            if (t < NST) computeStage(t, r, B);
        }
        LGKM0(); BAR();                 // all reads of ring[g&1] complete
        if (g + 2 < NSUP) issueSuper(g + 2);
    }
}

extern "C" void kernel_launch(void* const* d_in, const int* in_sizes, int n_in,
                              void* d_out, int out_size, void* d_ws, size_t ws_size,
                              hipStream_t stream) {
    const float* Yl  = (const float*)d_in[0];
    const float* Yhr = (const float*)d_in[1];
    const float* Yhi = (const float*)d_in[2];
    const float* g0o = (const float*)d_in[3];
    const float* g1o = (const float*)d_in[4];
    float* outp = (float*)d_out;
    dim3 grid(256, 1);   // one plane per block
    dim3 block(128);
    hipLaunchKernelGGL(dtcwt_inv, grid, block, 0, stream,
                       Yl, Yhr, Yhi, g0o, g1o, outp);
}

// Round 17
// 55.512 us; speedup vs baseline: 1.7555x; 1.7555x over previous
//
#include <hip/hip_runtime.h>

// Inverse DTCWT (biort legall) — FINAL: round-15 optimum restored.
// TH=128 (512 blocks, 2/CU co-resident, 4 waves/CU — measured optimum of the
// occupancy curve 2/4/10 waves), superstages of 4 row-pairs (ring-2 32KB),
// counted WAIT(16) ladder (never vmcnt 0 mid-loop), NT output stores
// (write stream bypasses L2/MALL: +17%), cached reads (NT reads regress:
// L2 absorbs ~25% of read requests). 2 output cols/thread, c2q in-register,
// column filter via register sliding window. 56.0 µs ≈ 6.1 TB/s logical
// ≈ 97% of achievable copy BW.

#define Hh 256
#define Ww 256
#define W2 128
#define SBsz (128 * 128)
#define TH 128
#define NST 66      // consumed row-pairs t = 0..65 (pairs ip0-1 .. ip0+64)
#define NSUP 17     // superstages of 4 pairs (last one half-used)
#define YBASE 6144  // Yl region float offset inside a super buffer
#define SUPSZ 8192  // floats per super buffer (32 KB)

typedef float f32x2 __attribute__((ext_vector_type(2)));

__device__ __forceinline__ int reflect_idx(int m, int N) {
    if (m < 0) m = -m - 1;
    if (m >= N) m = 2 * N - 1 - m;
    return m;
}

#define WAIT16() asm volatile("s_waitcnt vmcnt(16)" ::: "memory")
#define WAIT0()  asm volatile("s_waitcnt vmcnt(0)" ::: "memory")
#define LGKM0()  asm volatile("s_waitcnt lgkmcnt(0)" ::: "memory")
#define BAR()    __builtin_amdgcn_s_barrier()

__global__ __launch_bounds__(128) void dtcwt_inv(
    const float* __restrict__ Yl,
    const float* __restrict__ Yhr,
    const float* __restrict__ Yhi,
    const float* __restrict__ g0o,
    const float* __restrict__ g1o,
    float* __restrict__ out)
{
    const float SC = 0.70710678118654752440f;  // sqrt(0.5)
    __shared__ float ring[2][SUPSZ];

    const int c = threadIdx.x;        // 0..127: output cols 2c, 2c+1
    const int plane = blockIdx.x;
    const int i0 = blockIdx.y * TH;
    const int ip0 = i0 >> 1;

    const float* yl  = Yl  + (size_t)plane * (Hh * Ww);
    const float* phr = Yhr + (size_t)plane * 6 * SBsz;
    const float* phi = Yhi + (size_t)plane * 6 * SBsz;
    float* outp = out + (size_t)plane * (Hh * Ww);

    float g0[3], g1[5];
#pragma unroll
    for (int t = 0; t < 3; ++t) g0[t] = g0o[t];
#pragma unroll
    for (int t = 0; t < 5; ++t) g1[t] = g1o[t];

    // Quad-col tables: qcols 2c-2 .. 2c+3 -> subband col (even slots) + parity.
    int jcs[3], vq[6];
#pragma unroll
    for (int k = 0; k < 6; ++k) {
        int qq = reflect_idx(2 * c - 2 + k, Ww);
        if ((k & 1) == 0) jcs[k >> 1] = qq >> 1;
        vq[k] = qq & 1;
    }
    const int ylc0 = reflect_idx(2 * c - 1, Ww);
    const int ylc3 = reflect_idx(2 * c + 2, Ww);

    // ---- superstage staging ----
    // Super buffer layout (floats): band b (0..5 real, 6..11 imag) rows r=0..3
    // at b*512 + r*128 + col; Yl rows rr=0..7 at YBASE + rr*256 + col.
    // 32 chunks of 1KB: chunks 0..23 = (band b, half h): rows 2h,2h+1;
    // chunks 24..31 = Yl row rr. Wave w issues chunks w*16 .. w*16+15.
    const int wv = c >> 6, lane = c & 63;
    auto issueSuper = [&](int g) {
        float* B = ring[g & 1];
#pragma unroll
        for (int rep = 0; rep < 16; ++rep) {
            const int chunk = wv * 16 + rep;
            const float* src;
            int dstoff;
            if (chunk < 24) {
                const int b = chunk >> 1, h = chunk & 1;
                int t = 4 * g + 2 * h + (lane >> 5);
                int v = ip0 - 1 + t;
                int ip = v < 0 ? 0 : (v > 127 ? 127 : v);
                const float* bq = (b < 6) ? phr + (size_t)b * SBsz
                                          : phi + (size_t)(b - 6) * SBsz;
                src = bq + ip * W2 + ((lane & 31) << 2);
                dstoff = b * 512 + h * 256;
            } else {
                const int rr = chunk - 24;
                int t = 4 * g + (rr >> 1);
                int v = ip0 - 1 + t;
                int ip = v < 0 ? 0 : (v > 127 ? 127 : v);
                src = yl + (size_t)(2 * ip + (rr & 1)) * Ww + (lane << 2);
                dstoff = YBASE + rr * 256;
            }
            __builtin_amdgcn_global_load_lds(
                (const __attribute__((address_space(1))) void*)src,
                (__attribute__((address_space(3))) void*)(B + dstoff),
                16, 0, 0);
        }
    };

    float w1a[4], w1b[4], w2a[4], w2b[4];  // column windows, cols 2c / 2c+1
    const float SCg1[5] = {g1[0]*SC, g1[1]*SC, g1[2]*SC, g1[3]*SC, g1[4]*SC};
    const float SCg0[3] = {g0[0]*SC, g0[1]*SC, g0[2]*SC};

    auto computeStage = [&](int t, int r, const float* B) {
        const int ro = r * 128;
        // Yl row filter, windows cols 2c-1 .. 2c+2 (rows 2r, 2r+1 of super)
        const int ya_o = YBASE + 512 * r, yb_o = ya_o + 256;
        float ya0 = B[ya_o + ylc0],    ya1 = B[ya_o + 2*c];
        float ya2 = B[ya_o + 2*c + 1], ya3 = B[ya_o + ylc3];
        float yb0 = B[yb_o + ylc0],    yb1 = B[yb_o + 2*c];
        float yb2 = B[yb_o + 2*c + 1], yb3 = B[yb_o + ylc3];
        float y1_00 = g0[0]*ya0 + g0[1]*ya1 + g0[2]*ya2;
        float y1_01 = g0[0]*ya1 + g0[1]*ya2 + g0[2]*ya3;
        float y1_10 = g0[0]*yb0 + g0[1]*yb1 + g0[2]*yb2;
        float y1_11 = g0[0]*yb1 + g0[1]*yb2 + g0[2]*yb3;
        float y2_00 = 0.f, y2_01 = 0.f, y2_10 = 0.f, y2_11 = 0.f;
#pragma unroll
        for (int m = 0; m < 3; ++m) {
            const int col = ro + jcs[m];
            float lr1 = B[col],        lr2 = B[2560 + col];   // lh 0,5
            float hr1 = B[1024 + col], hr2 = B[1536 + col];   // hl 2,3
            float er1 = B[512 + col],  er2 = B[2048 + col];   // hh 1,4
            float li1 = B[3072 + col],        li2 = B[3072 + 2560 + col];
            float hi1 = B[3072 + 1024 + col], hi2 = B[3072 + 1536 + col];
            float ei1 = B[3072 + 512 + col],  ei2 = B[3072 + 2048 + col];
            float lSr = lr1 + lr2, lSi = li1 + li2, lDi = li1 - li2, lDr = lr2 - lr1;
            float hSr = hr1 + hr2, hSi = hi1 + hi2, hDi = hi1 - hi2, hDr = hr2 - hr1;
            float eSr = er1 + er2, eSi = ei1 + ei2, eDi = ei1 - ei2, eDr = er2 - er1;
#pragma unroll
            for (int kk = 0; kk < 2; ++kk) {
                const int k = 2 * m + kk;
                const int vv = vq[k];
                float qh0 = vv ? hSi : hSr, qh1 = vv ? hDr : hDi;
                float qe0 = vv ? eSi : eSr, qe1 = vv ? eDr : eDi;
                float ql0 = vv ? lSi : lSr, ql1 = vv ? lDr : lDi;
                if (k <= 4) {
                    y1_00 += SCg1[k] * qh0; y1_10 += SCg1[k] * qh1;
                    y2_00 += SCg1[k] * qe0; y2_10 += SCg1[k] * qe1;
                }
                if (k >= 1) {
                    y1_01 += SCg1[k - 1] * qh0; y1_11 += SCg1[k - 1] * qh1;
                    y2_01 += SCg1[k - 1] * qe0; y2_11 += SCg1[k - 1] * qe1;
                }
                if (k >= 1 && k <= 3) {
                    y2_00 += SCg0[k - 1] * ql0; y2_10 += SCg0[k - 1] * ql1;
                }
                if (k >= 2 && k <= 4) {
                    y2_01 += SCg0[k - 2] * ql0; y2_11 += SCg0[k - 2] * ql1;
                }
            }
        }
        // vertical reflection order + column-filter sliding window
        int v = ip0 - 1 + t;
        bool rev = (v < 0) || (v > 127);
        float a1A = rev ? y1_10 : y1_00, a2A = rev ? y2_10 : y2_00;
        float b1A = rev ? y1_00 : y1_10, b2A = rev ? y2_00 : y2_10;
        float a1B = rev ? y1_11 : y1_01, a2B = rev ? y2_11 : y2_01;
        float b1B = rev ? y1_01 : y1_11, b2B = rev ? y2_01 : y2_11;
        if (t == 0) {
            w1a[0]=a1A; w1a[1]=b1A; w2a[0]=a2A; w2a[1]=b2A;
            w1b[0]=a1B; w1b[1]=b1B; w2b[0]=a2B; w2b[1]=b2B;
        } else if (t == 1) {
            w1a[2]=a1A; w1a[3]=b1A; w2a[2]=a2A; w2a[3]=b2A;
            w1b[2]=a1B; w1b[3]=b1B; w2b[2]=a2B; w2b[3]=b2B;
        } else {
            const int r0 = i0 + 2 * (t - 2);
            float o0A = g0[0]*w1a[1] + g0[1]*w1a[2] + g0[2]*w1a[3]
                      + g1[0]*w2a[0] + g1[1]*w2a[1] + g1[2]*w2a[2]
                      + g1[3]*w2a[3] + g1[4]*a2A;
            float o1A = g0[0]*w1a[2] + g0[1]*w1a[3] + g0[2]*a1A
                      + g1[0]*w2a[1] + g1[1]*w2a[2] + g1[2]*w2a[3]
                      + g1[3]*a2A + g1[4]*b2A;
            float o0B = g0[0]*w1b[1] + g0[1]*w1b[2] + g0[2]*w1b[3]
                      + g1[0]*w2b[0] + g1[1]*w2b[1] + g1[2]*w2b[2]
                      + g1[3]*w2b[3] + g1[4]*a2B;
            float o1B = g0[0]*w1b[2] + g0[1]*w1b[3] + g0[2]*a1B
                      + g1[0]*w2b[1] + g1[1]*w2b[2] + g1[2]*w2b[3]
                      + g1[3]*a2B + g1[4]*b2B;
            f32x2 v0; v0.x = o0A; v0.y = o0B;
            f32x2 v1; v1.x = o1A; v1.y = o1B;
            __builtin_nontemporal_store(v0, (f32x2*)(outp + (size_t)r0 * Ww + 2 * c));
            __builtin_nontemporal_store(v1, (f32x2*)(outp + (size_t)(r0 + 1) * Ww + 2 * c));
            w1a[0]=w1a[2]; w1a[1]=w1a[3]; w1a[2]=a1A; w1a[3]=b1A;
            w2a[0]=w2a[2]; w2a[1]=w2a[3]; w2a[2]=a2A; w2a[3]=b2A;
            w1b[0]=w1b[2]; w1b[1]=w1b[3]; w1b[2]=a1B; w1b[3]=b1B;
            w2b[0]=w2b[2]; w2b[1]=w2b[3]; w2b[2]=a2B; w2b[3]=b2B;
        }
    };

    // ---- pipeline over superstages: counted WAIT(16), never 0 mid-loop ----
    issueSuper(0); issueSuper(1);
    for (int g = 0; g < NSUP; ++g) {
        if (g + 1 < NSUP) { WAIT16(); } else { WAIT0(); }
        LGKM0(); BAR();                 // super g fully landed (both waves)
        const float* B = ring[g & 1];
#pragma unroll
        for (int r = 0; r < 4; ++r) {
            const int t = 4 * g + r;
            if (t < NST) computeStage(t, r, B);
        }
        LGKM0(); BAR();                 // all reads of ring[g&1] complete
        if (g + 2 < NSUP) issueSuper(g + 2);
    }
}

extern "C" void kernel_launch(void* const* d_in, const int* in_sizes, int n_in,
                              void* d_out, int out_size, void* d_ws, size_t ws_size,
                              hipStream_t stream) {
    const float* Yl  = (const float*)d_in[0];
    const float* Yhr = (const float*)d_in[1];
    const float* Yhi = (const float*)d_in[2];
    const float* g0o = (const float*)d_in[3];
    const float* g1o = (const float*)d_in[4];
    float* outp = (float*)d_out;
    dim3 grid(256, Hh / TH);   // 256 planes x 2 row tiles
    dim3 block(128);
    hipLaunchKernelGGL(dtcwt_inv, grid, block, 0, stream,
                       Yl, Yhr, Yhi, g0o, g1o, outp);
}